// Round 3
// baseline (276.591 us; speedup 1.0000x reference)
//
#include <hip/hip_runtime.h>

// B=2, S=2048, D=1024, H=16, DK=64.  BH = 32, M = B*S = 4096.
// convert -> qkv_gemm (dbuf, coalesced LDS epilogue, Q pre-scaled log2e/8)
// -> attn (flash, barrier-free: K/V fragments direct from global via L1,
//          register dbuf K, register-only P, l via ones-MFMA) -> ln.

typedef float f32x4 __attribute__((ext_vector_type(4)));
typedef short short8 __attribute__((ext_vector_type(8)));
typedef unsigned int uint32x4 __attribute__((ext_vector_type(4)));

__device__ __forceinline__ unsigned short f2bf(float f) {
    unsigned u = __builtin_bit_cast(unsigned, f);
    u += 0x7fffu + ((u >> 16) & 1u);          // round-to-nearest-even
    return (unsigned short)(u >> 16);
}
// pack two floats -> two bf16 (truncation) in ONE v_perm_b32
__device__ __forceinline__ unsigned packbf2(float lo, float hi) {
    return __builtin_amdgcn_perm(__builtin_bit_cast(unsigned, hi),
                                 __builtin_bit_cast(unsigned, lo), 0x07060302u);
}

// async global->LDS, 16 B per lane; dest = wave-uniform base + lane*16
__device__ __forceinline__ void g2l16(const unsigned short* g, unsigned short* l) {
    __builtin_amdgcn_global_load_lds(
        (const __attribute__((address_space(1))) unsigned int*)g,
        (__attribute__((address_space(3))) unsigned int*)l, 16, 0, 0);
}

// ---------------------------------------------------------------------------
// Kernel 0: merged converts (X -> bf16; W -> W^T bf16).
// ---------------------------------------------------------------------------
__global__ __launch_bounds__(256) void convert_all(
    const float* __restrict__ xq, const float* __restrict__ xk, const float* __restrict__ xv,
    const float* __restrict__ Wq, const float* __restrict__ Wk, const float* __restrict__ Wv,
    unsigned short* __restrict__ xout, unsigned short* __restrict__ wout)
{
    const int bx  = blockIdx.x;
    const int tid = threadIdx.x;
    if (bx < 6144) {
        const int z = bx >> 11;
        const float* src = (z == 0) ? xq : (z == 1) ? xk : xv;
        const size_t idx = ((size_t)(bx & 2047) * 256 + tid) * 8;
        const float4 a = *(const float4*)(src + idx);
        const float4 b = *(const float4*)(src + idx + 4);
        short8 o;
        o[0] = (short)f2bf(a.x); o[1] = (short)f2bf(a.y);
        o[2] = (short)f2bf(a.z); o[3] = (short)f2bf(a.w);
        o[4] = (short)f2bf(b.x); o[5] = (short)f2bf(b.y);
        o[6] = (short)f2bf(b.z); o[7] = (short)f2bf(b.w);
        *(short8*)(xout + (size_t)z * 4194304 + idx) = o;
    } else {
        const int i = bx - 6144;
        const int z = i >> 8, tile = i & 255;
        const float* W = (z == 0) ? Wq : (z == 1) ? Wk : Wv;
        unsigned short* Wt = wout + (size_t)z * 1048576;
        __shared__ unsigned short Ts[64 * 65];
        const int kb0 = (tile >> 4) * 64, nb0 = (tile & 15) * 64;
        const int a = tid >> 6, b = tid & 63;
#pragma unroll
        for (int j = 0; j < 16; ++j) {
            const int k = j * 4 + a, n = b;
            Ts[n * 65 + k] = f2bf(W[(size_t)(kb0 + k) * 1024 + nb0 + n]);
        }
        __syncthreads();
#pragma unroll
        for (int j = 0; j < 16; ++j) {
            const int n = j * 4 + a, k = b;
            Wt[(size_t)(nb0 + n) * 1024 + kb0 + k] = Ts[n * 65 + k];
        }
    }
}

// ---------------------------------------------------------------------------
// Kernel 1: QKV GEMM (bf16, 128x128 tile, BK=32, dbuf prefetch-after-barrier).
// Q,K -> [B,H,S,DK]; V -> [B,H,DK,Sperm] with per-32 slot-perm matching the
// attn S^T register layout: value at s-local i stored at slot
//   p = ((i>>2)&3)*8 + (i&3) + ((i>>4)&1)*4   (within each 32-block).
// ---------------------------------------------------------------------------
__global__ __launch_bounds__(256) void qkv_gemm(
    const unsigned short* __restrict__ Xb, const unsigned short* __restrict__ Wtb,
    const float* __restrict__ bq, const float* __restrict__ bk, const float* __restrict__ bv,
    unsigned short* __restrict__ qo, unsigned short* __restrict__ ko, unsigned short* __restrict__ vo)
{
    const int z = blockIdx.z;
    const unsigned short* X  = Xb  + (size_t)z * 4194304;
    const unsigned short* Wt = Wtb + (size_t)z * 1048576;
    const float* bias   = (z == 0) ? bq : (z == 1) ? bk : bv;
    unsigned short* out = (z == 0) ? qo : (z == 1) ? ko : vo;

    __shared__ unsigned short smem[16384];    // 32 KB: dbuf A|B; epilogue reuses

    const int tid  = threadIdx.x;
    const int wave = tid >> 6;
    const int lane = tid & 63;
    const int l15  = lane & 15;
    const int quad = lane >> 4;
    const int mq   = wave & 1, nq = wave >> 1;
    const int mbase = blockIdx.x * 128, nbase = blockIdx.y * 128;

    const int srow = lane >> 2;
    const int schk = (lane & 3) ^ (srow & 3);

    const unsigned short* srcA = X  + (size_t)(mbase + wave * 32 + srow) * 1024 + schk * 8;
    const unsigned short* srcB = Wt + (size_t)(nbase + wave * 32 + srow) * 1024 + schk * 8;

    f32x4 acc[4][4];
#pragma unroll
    for (int i = 0; i < 4; ++i)
#pragma unroll
        for (int j = 0; j < 4; ++j) acc[i][j] = (f32x4){0.f, 0.f, 0.f, 0.f};

#pragma unroll
    for (int t = 0; t < 2; ++t) {
        g2l16(srcA + (size_t)t * 16 * 1024, &smem[(wave * 32 + t * 16) * 32]);
        g2l16(srcB + (size_t)t * 16 * 1024, &smem[4096 + (wave * 32 + t * 16) * 32]);
    }

    for (int it = 0; it < 32; ++it) {
        const int boff = (it & 1) * 8192;
        __syncthreads();

        if (it + 1 < 32) {
            const int poff = boff ^ 8192;
            const size_t ko2 = (size_t)(it + 1) * 32;
#pragma unroll
            for (int t = 0; t < 2; ++t) {
                g2l16(srcA + (size_t)t * 16 * 1024 + ko2, &smem[poff + (wave * 32 + t * 16) * 32]);
                g2l16(srcB + (size_t)t * 16 * 1024 + ko2, &smem[poff + 4096 + (wave * 32 + t * 16) * 32]);
            }
        }

        short8 af[4], bf[4];
#pragma unroll
        for (int i = 0; i < 4; ++i) {
            af[i] = *(const short8*)(&smem[boff + (mq * 64 + i * 16 + l15) * 32 + ((quad ^ (l15 & 3)) << 3)]);
            bf[i] = *(const short8*)(&smem[boff + 4096 + (nq * 64 + i * 16 + l15) * 32 + ((quad ^ (l15 & 3)) << 3)]);
        }
#pragma unroll
        for (int mt = 0; mt < 4; ++mt)
#pragma unroll
            for (int nt = 0; nt < 4; ++nt)
                acc[mt][nt] = __builtin_amdgcn_mfma_f32_16x16x32_bf16(af[mt], bf[nt], acc[mt][nt], 0, 0, 0);
    }

    __syncthreads();

    float bvals[4];
#pragma unroll
    for (int nt = 0; nt < 4; ++nt) bvals[nt] = bias[nbase + nq * 64 + nt * 16 + l15];

    if (z == 2) {
        // ---- V^T epilogue: block transpose, per-32 slot permutation.
        unsigned short* Epv = smem;            // [32 rows][136]
        const int hbase = nbase >> 6;
        const int b     = mbase >> 11;
        const int srow0 = mbase & 2047;
#pragma unroll
        for (int nt = 0; nt < 4; ++nt) {
            __syncthreads();
            short8 w[2];
#pragma unroll
            for (int e = 0; e < 2; ++e)
#pragma unroll
                for (int j = 0; j < 8; ++j) {
                    const int mt2 = 2 * e + (j >> 2), r = j & 3;
                    w[e][j] = (short)f2bf(acc[mt2][nt][r] + bvals[nt]);
                }
            unsigned short* dst = &Epv[(nq * 16 + l15) * 136 + mq * 64 + quad * 8];
            *(short8*)(dst)      = w[0];
            *(short8*)(dst + 32) = w[1];
            __syncthreads();
            const int row = tid >> 3;                    // 0..31
            const int d   = nt * 16 + (row & 15);
            const int h   = hbase + (row >> 4);
#pragma unroll
            for (int e = 0; e < 2; ++e) {
                const int colb = e * 64 + (tid & 7) * 8;
                short8 v = *(const short8*)(&Epv[row * 136 + colb]);
                *(short8*)(&out[((size_t)(b * 16 + h) * 64 + d) * 2048 + srow0 + colb]) = v;
            }
        }
    } else {
        // ---- Q/K epilogue: wave-local transpose -> 1 KB-contiguous stores
        unsigned short* Ep = smem + wave * 1152;         // [16 m][72]
        const int hQ = (nbase + nq * 64) >> 6;
        const float scl = (z == 0) ? 0.18033688f : 1.0f; // log2(e)/8 folded into Q
#pragma unroll
        for (int mt = 0; mt < 4; ++mt) {
#pragma unroll
            for (int nt = 0; nt < 4; ++nt)
#pragma unroll
                for (int r = 0; r < 4; ++r)
                    Ep[(quad * 4 + r) * 72 + nt * 16 + l15] =
                        f2bf((acc[mt][nt][r] + bvals[nt]) * scl);
#pragma unroll
            for (int half = 0; half < 2; ++half) {
                const int m = (lane >> 3) + half * 8;
                const int nblk = lane & 7;
                short8 v = *(const short8*)(&Ep[m * 72 + nblk * 8]);
                const int gm = mbase + mq * 64 + mt * 16 + m;
                const int b2 = gm >> 11, srw = gm & 2047;
                *(short8*)(&out[((size_t)(b2 * 16 + hQ) * 2048 + srw) * 64 + nblk * 8]) = v;
            }
        }
    }
}

// ---------------------------------------------------------------------------
// Kernel 2: flash attention, barrier-free.
//   4 independent waves per block; each wave owns 32 q-rows and iterates all
//   32 KV tiles.  K/V fragments are read DIRECTLY from global (coalesced
//   16 B/lane; all 4 waves of a block issue identical K/V addresses -> L1
//   absorbs the redundancy).  K register-double-buffered (kfa/kfb), V issued
//   one compute-phase ahead.  NO __syncthreads anywhere.
//   S^T = mfma(A=K, B=Q); p = exp2 in regs; pack -> P B-frag;
//   O^T = mfma(A=V^T, B=P); l via ones-MFMA (lacc[nt][0] = full column sum,
//   per-lane exact -> normalization folded into the O store).
//   Epilogue: wave-private LDS transpose (XOR-swizzled) -> coalesced stores.
// ---------------------------------------------------------------------------
__global__ __launch_bounds__(256) void attn(
    const unsigned short* __restrict__ qb, const unsigned short* __restrict__ kb,
    const unsigned short* __restrict__ vtb, float* __restrict__ xw)
{
    const int tid  = threadIdx.x;
    const int wave = tid >> 6;            // 0..3
    const int lane = tid & 63;
    const int l15  = lane & 15;
    const int quad = lane >> 4;

    const int bh    = blockIdx.x;
    const int qbase = blockIdx.y * 128 + wave * 32;

    __shared__ __align__(16) float Ow[4][2048];     // 32 KB, wave-private epilogue

    // Q fragments, 2 q-tiles (pre-scaled by log2e/8)
    short8 qf[2][2];
#pragma unroll
    for (int nt = 0; nt < 2; ++nt) {
        const unsigned short* Qp = qb + ((size_t)bh * 2048 + qbase + nt * 16 + l15) * 64 + quad * 8;
        qf[nt][0] = *(const short8*)(Qp);
        qf[nt][1] = *(const short8*)(Qp + 32);
    }

    // per-lane fragment base pointers (element units)
    //   kf[mt][dc](it) = K[it*64 + mt*16 + l15][dc*32 + quad*8 .. +8]
    //   vf[dt][c](it)  = V^T[dt*16 + l15][it*64 + c*32 + quad*8 .. +8]
    const unsigned short* Kl = kb  + (size_t)bh * 2048 * 64 + (size_t)l15 * 64   + quad * 8;
    const unsigned short* Vl = vtb + (size_t)bh * 64 * 2048 + (size_t)l15 * 2048 + quad * 8;

    // all-ones bf16 A-fragment for the l row-sum MFMA
    uint32x4 ou; ou[0] = ou[1] = ou[2] = ou[3] = 0x3F803F80u;
    const short8 onesf = __builtin_bit_cast(short8, ou);

    f32x4 lacc[2];
    f32x4 O[2][4];                      // O^T: [q-tile nt][d-tile dt]
#pragma unroll
    for (int nt = 0; nt < 2; ++nt) {
        lacc[nt] = (f32x4){0.f, 0.f, 0.f, 0.f};
#pragma unroll
        for (int i = 0; i < 4; ++i) O[nt][i] = (f32x4){0.f, 0.f, 0.f, 0.f};
    }

    short8 kfa[4][2], kfb[4][2], vf[4][2];

    auto loadK = [&](short8 (&kf)[4][2], int it) {
        const unsigned short* p = Kl + it * 4096;
#pragma unroll
        for (int mt = 0; mt < 4; ++mt) {
            kf[mt][0] = *(const short8*)(p + mt * 1024);
            kf[mt][1] = *(const short8*)(p + mt * 1024 + 32);
        }
    };
    auto loadV = [&](int it) {
        const unsigned short* p = Vl + it * 64;
#pragma unroll
        for (int dt = 0; dt < 4; ++dt) {
            vf[dt][0] = *(const short8*)(p + dt * 32768);
            vf[dt][1] = *(const short8*)(p + dt * 32768 + 32);
        }
    };
    auto compute = [&](const short8 (&kf)[4][2]) {
        // ---- S^T tiles: sc[mt][nt] holds S^T[s=mt*16+quad*4+r][q=nt*16+l15]
        f32x4 sc[4][2];
#pragma unroll
        for (int mt = 0; mt < 4; ++mt)
#pragma unroll
            for (int nt = 0; nt < 2; ++nt) {
                f32x4 a = {0.f, 0.f, 0.f, 0.f};
                a = __builtin_amdgcn_mfma_f32_16x16x32_bf16(kf[mt][0], qf[nt][0], a, 0, 0, 0);
                a = __builtin_amdgcn_mfma_f32_16x16x32_bf16(kf[mt][1], qf[nt][1], a, 0, 0, 0);
                sc[mt][nt] = a;
            }
        // ---- p = exp2(s) in regs
#pragma unroll
        for (int mt = 0; mt < 4; ++mt)
#pragma unroll
            for (int nt = 0; nt < 2; ++nt)
#pragma unroll
                for (int r = 0; r < 4; ++r)
                    sc[mt][nt][r] = __builtin_amdgcn_exp2f(sc[mt][nt][r]);
        // ---- PV + l: O^T += V^T(A) . P(B);  lacc += ones . P
#pragma unroll
        for (int c = 0; c < 2; ++c) {
            short8 pf[2];
#pragma unroll
            for (int nt = 0; nt < 2; ++nt) {
                uint32x4 pu;
                pu[0] = packbf2(sc[2 * c][nt][0],     sc[2 * c][nt][1]);
                pu[1] = packbf2(sc[2 * c][nt][2],     sc[2 * c][nt][3]);
                pu[2] = packbf2(sc[2 * c + 1][nt][0], sc[2 * c + 1][nt][1]);
                pu[3] = packbf2(sc[2 * c + 1][nt][2], sc[2 * c + 1][nt][3]);
                pf[nt] = __builtin_bit_cast(short8, pu);
            }
            lacc[0] = __builtin_amdgcn_mfma_f32_16x16x32_bf16(onesf, pf[0], lacc[0], 0, 0, 0);
            lacc[1] = __builtin_amdgcn_mfma_f32_16x16x32_bf16(onesf, pf[1], lacc[1], 0, 0, 0);
#pragma unroll
            for (int dt = 0; dt < 4; ++dt) {
                O[0][dt] = __builtin_amdgcn_mfma_f32_16x16x32_bf16(vf[dt][c], pf[0], O[0][dt], 0, 0, 0);
                O[1][dt] = __builtin_amdgcn_mfma_f32_16x16x32_bf16(vf[dt][c], pf[1], O[1][dt], 0, 0, 0);
            }
        }
    };

    // ---- main loop: K reg-dbuf (kfa/kfb), V issued a phase ahead, no barriers
    loadK(kfa, 0);
#pragma unroll 1
    for (int it = 0; it < 32; it += 2) {
        loadK(kfb, it + 1);        // prefetch next K tile
        loadV(it);                 // V for current tile (consumed after QK^T)
        compute(kfa);
        if (it + 2 < 32) loadK(kfa, it + 2);
        loadV(it + 1);
        compute(kfb);
    }

    // ---- epilogue: normalize (per-lane exact l), wave-private LDS transpose
    const float inv0 = 1.0f / lacc[0][0];
    const float inv1 = 1.0f / lacc[1][0];
    float* Owp = &Ow[wave][0];
#pragma unroll
    for (int nt = 0; nt < 2; ++nt) {
        const float iv = nt ? inv1 : inv0;
#pragma unroll
        for (int dt = 0; dt < 4; ++dt) {
            f32x4 v = O[nt][dt];
            v[0] *= iv; v[1] *= iv; v[2] *= iv; v[3] *= iv;
            const int row = nt * 16 + l15;
            const int c4s = (dt * 4 + quad) ^ l15;      // swizzle: col4 ^ (row&15)
            *(f32x4*)(&Owp[row * 64 + c4s * 4]) = v;
        }
    }
    const int b = bh >> 4, h = bh & 15;
    const size_t obase = ((size_t)b * 2048 + qbase) * 1024 + h * 64 + lane;
#pragma unroll
    for (int qq = 0; qq < 32; ++qq)
        xw[obase + (size_t)qq * 1024] =
            Owp[qq * 64 + ((((lane >> 2) ^ (qq & 15)) << 2) | (lane & 3))];
}

// ---------------------------------------------------------------------------
// Kernel 3: residual + LayerNorm (eps = 1e-6).  One block per (b,s) row.
// ---------------------------------------------------------------------------
__global__ __launch_bounds__(256) void ln_kernel(
    const float* __restrict__ xw, const float* __restrict__ res,
    const float* __restrict__ gamma, const float* __restrict__ beta,
    float* __restrict__ out)
{
    const int row = blockIdx.x;
    const int tid = threadIdx.x;
    const size_t base = (size_t)row * 1024 + tid * 4;

    const float4 x  = *(const float4*)(xw + base);
    const float4 rv = *(const float4*)(res + base);
    float4 y;
    y.x = x.x + rv.x; y.y = x.y + rv.y; y.z = x.z + rv.z; y.w = x.w + rv.w;

    float s  = y.x + y.y + y.z + y.w;
    float s2 = y.x * y.x + y.y * y.y + y.z * y.z + y.w * y.w;
#pragma unroll
    for (int off = 32; off >= 1; off >>= 1) {
        s  += __shfl_xor(s, off);
        s2 += __shfl_xor(s2, off);
    }
    __shared__ float red[8];
    const int wave = tid >> 6;
    if ((tid & 63) == 0) { red[wave] = s; red[4 + wave] = s2; }
    __syncthreads();
    s  = red[0] + red[1] + red[2] + red[3];
    s2 = red[4] + red[5] + red[6] + red[7];

    const float mu   = s * (1.0f / 1024.0f);
    const float var  = s2 * (1.0f / 1024.0f) - mu * mu;
    const float rstd = rsqrtf(var + 1e-6f);

    const float4 g  = *(const float4*)(gamma + tid * 4);
    const float4 bt = *(const float4*)(beta + tid * 4);
    float4 o;
    o.x = (y.x - mu) * rstd * g.x + bt.x;
    o.y = (y.y - mu) * rstd * g.y + bt.y;
    o.z = (y.z - mu) * rstd * g.z + bt.z;
    o.w = (y.w - mu) * rstd * g.w + bt.w;
    *(float4*)(out + base) = o;
}

// ---------------------------------------------------------------------------
extern "C" void kernel_launch(void* const* d_in, const int* in_sizes, int n_in,
                              void* d_out, int out_size, void* d_ws, size_t ws_size,
                              hipStream_t stream) {
    const float* query = (const float*)d_in[0];
    const float* key_  = (const float*)d_in[1];
    const float* value = (const float*)d_in[2];
    const float* Wq    = (const float*)d_in[3];
    const float* bq    = (const float*)d_in[4];
    const float* Wk    = (const float*)d_in[5];
    const float* bk    = (const float*)d_in[6];
    const float* Wv    = (const float*)d_in[7];
    const float* bv    = (const float*)d_in[8];
    const float* ln_g  = (const float*)d_in[9];
    const float* ln_b  = (const float*)d_in[10];
    float* out = (float*)d_out;

    // ws layout (54 MB): [0,24M) Xb (dead after qkv; aliased by xw 16 MB),
    // [24,30M) Wtb, [30,38M) qb, [38,46M) kb, [46,54M) vtb
    const size_t MB = 1024 * 1024;
    char* ws = (char*)d_ws;
    unsigned short* Xbuf = (unsigned short*)(ws);
    float*          xwp  = (float*)(ws);
    unsigned short* Wtb  = (unsigned short*)(ws + 24 * MB);
    unsigned short* qbuf = (unsigned short*)(ws + 30 * MB);
    unsigned short* kbuf = (unsigned short*)(ws + 38 * MB);
    unsigned short* vtb  = (unsigned short*)(ws + 46 * MB);

    convert_all<<<6912,           256, 0, stream>>>(query, key_, value, Wq, Wk, Wv, Xbuf, Wtb);
    qkv_gemm   <<<dim3(32, 8, 3), 256, 0, stream>>>(Xbuf, Wtb, bq, bk, bv, qbuf, kbuf, vtb);
    attn       <<<dim3(32, 16),   256, 0, stream>>>(qbuf, kbuf, vtb, xwp);
    ln_kernel  <<<4096,           256, 0, stream>>>(xwp, query, ln_g, ln_b, out);
}

// Round 4
// 205.047 us; speedup vs baseline: 1.3489x; 1.3489x over previous
//
#include <hip/hip_runtime.h>

// B=2, S=2048, D=1024, H=16, DK=64.  BH = 32, M = B*S = 4096.
// convert -> qkv_gemm (dbuf, coalesced LDS epilogue, Q pre-scaled log2e/8)
// -> attn (flash, KV-split 8-wave blocks, register-only P, l via ones-MFMA,
//          QK/exp interleave + block stagger + setprio) -> ln.

typedef float f32x4 __attribute__((ext_vector_type(4)));
typedef short short8 __attribute__((ext_vector_type(8)));
typedef unsigned int uint32x4 __attribute__((ext_vector_type(4)));

__device__ __forceinline__ unsigned short f2bf(float f) {
    unsigned u = __builtin_bit_cast(unsigned, f);
    u += 0x7fffu + ((u >> 16) & 1u);          // round-to-nearest-even
    return (unsigned short)(u >> 16);
}
// pack two floats -> two bf16 (truncation) in ONE v_perm_b32
__device__ __forceinline__ unsigned packbf2(float lo, float hi) {
    return __builtin_amdgcn_perm(__builtin_bit_cast(unsigned, hi),
                                 __builtin_bit_cast(unsigned, lo), 0x07060302u);
}

// async global->LDS, 16 B per lane; dest = wave-uniform base + lane*16
__device__ __forceinline__ void g2l16(const unsigned short* g, unsigned short* l) {
    __builtin_amdgcn_global_load_lds(
        (const __attribute__((address_space(1))) unsigned int*)g,
        (__attribute__((address_space(3))) unsigned int*)l, 16, 0, 0);
}

// ---------------------------------------------------------------------------
// Kernel 0: merged converts (X -> bf16; W -> W^T bf16).
// ---------------------------------------------------------------------------
__global__ __launch_bounds__(256) void convert_all(
    const float* __restrict__ xq, const float* __restrict__ xk, const float* __restrict__ xv,
    const float* __restrict__ Wq, const float* __restrict__ Wk, const float* __restrict__ Wv,
    unsigned short* __restrict__ xout, unsigned short* __restrict__ wout)
{
    const int bx  = blockIdx.x;
    const int tid = threadIdx.x;
    if (bx < 6144) {
        const int z = bx >> 11;
        const float* src = (z == 0) ? xq : (z == 1) ? xk : xv;
        const size_t idx = ((size_t)(bx & 2047) * 256 + tid) * 8;
        const float4 a = *(const float4*)(src + idx);
        const float4 b = *(const float4*)(src + idx + 4);
        short8 o;
        o[0] = (short)f2bf(a.x); o[1] = (short)f2bf(a.y);
        o[2] = (short)f2bf(a.z); o[3] = (short)f2bf(a.w);
        o[4] = (short)f2bf(b.x); o[5] = (short)f2bf(b.y);
        o[6] = (short)f2bf(b.z); o[7] = (short)f2bf(b.w);
        *(short8*)(xout + (size_t)z * 4194304 + idx) = o;
    } else {
        const int i = bx - 6144;
        const int z = i >> 8, tile = i & 255;
        const float* W = (z == 0) ? Wq : (z == 1) ? Wk : Wv;
        unsigned short* Wt = wout + (size_t)z * 1048576;
        __shared__ unsigned short Ts[64 * 65];
        const int kb0 = (tile >> 4) * 64, nb0 = (tile & 15) * 64;
        const int a = tid >> 6, b = tid & 63;
#pragma unroll
        for (int j = 0; j < 16; ++j) {
            const int k = j * 4 + a, n = b;
            Ts[n * 65 + k] = f2bf(W[(size_t)(kb0 + k) * 1024 + nb0 + n]);
        }
        __syncthreads();
#pragma unroll
        for (int j = 0; j < 16; ++j) {
            const int n = j * 4 + a, k = b;
            Wt[(size_t)(nb0 + n) * 1024 + kb0 + k] = Ts[n * 65 + k];
        }
    }
}

// ---------------------------------------------------------------------------
// Kernel 1: QKV GEMM (bf16, 128x128 tile, BK=32, dbuf prefetch-after-barrier).
// Q,K -> [B,H,S,DK]; V -> [B,H,DK,Sperm] with per-32 slot-perm matching the
// attn S^T register layout: value at s-local i stored at slot
//   p = ((i>>2)&3)*8 + (i&3) + ((i>>4)&1)*4   (within each 32-block).
// ---------------------------------------------------------------------------
__global__ __launch_bounds__(256) void qkv_gemm(
    const unsigned short* __restrict__ Xb, const unsigned short* __restrict__ Wtb,
    const float* __restrict__ bq, const float* __restrict__ bk, const float* __restrict__ bv,
    unsigned short* __restrict__ qo, unsigned short* __restrict__ ko, unsigned short* __restrict__ vo)
{
    const int z = blockIdx.z;
    const unsigned short* X  = Xb  + (size_t)z * 4194304;
    const unsigned short* Wt = Wtb + (size_t)z * 1048576;
    const float* bias   = (z == 0) ? bq : (z == 1) ? bk : bv;
    unsigned short* out = (z == 0) ? qo : (z == 1) ? ko : vo;

    __shared__ unsigned short smem[16384];    // 32 KB: dbuf A|B; epilogue reuses

    const int tid  = threadIdx.x;
    const int wave = tid >> 6;
    const int lane = tid & 63;
    const int l15  = lane & 15;
    const int quad = lane >> 4;
    const int mq   = wave & 1, nq = wave >> 1;
    const int mbase = blockIdx.x * 128, nbase = blockIdx.y * 128;

    const int srow = lane >> 2;
    const int schk = (lane & 3) ^ (srow & 3);

    const unsigned short* srcA = X  + (size_t)(mbase + wave * 32 + srow) * 1024 + schk * 8;
    const unsigned short* srcB = Wt + (size_t)(nbase + wave * 32 + srow) * 1024 + schk * 8;

    f32x4 acc[4][4];
#pragma unroll
    for (int i = 0; i < 4; ++i)
#pragma unroll
        for (int j = 0; j < 4; ++j) acc[i][j] = (f32x4){0.f, 0.f, 0.f, 0.f};

#pragma unroll
    for (int t = 0; t < 2; ++t) {
        g2l16(srcA + (size_t)t * 16 * 1024, &smem[(wave * 32 + t * 16) * 32]);
        g2l16(srcB + (size_t)t * 16 * 1024, &smem[4096 + (wave * 32 + t * 16) * 32]);
    }

    for (int it = 0; it < 32; ++it) {
        const int boff = (it & 1) * 8192;
        __syncthreads();

        if (it + 1 < 32) {
            const int poff = boff ^ 8192;
            const size_t ko2 = (size_t)(it + 1) * 32;
#pragma unroll
            for (int t = 0; t < 2; ++t) {
                g2l16(srcA + (size_t)t * 16 * 1024 + ko2, &smem[poff + (wave * 32 + t * 16) * 32]);
                g2l16(srcB + (size_t)t * 16 * 1024 + ko2, &smem[poff + 4096 + (wave * 32 + t * 16) * 32]);
            }
        }

        short8 af[4], bf[4];
#pragma unroll
        for (int i = 0; i < 4; ++i) {
            af[i] = *(const short8*)(&smem[boff + (mq * 64 + i * 16 + l15) * 32 + ((quad ^ (l15 & 3)) << 3)]);
            bf[i] = *(const short8*)(&smem[boff + 4096 + (nq * 64 + i * 16 + l15) * 32 + ((quad ^ (l15 & 3)) << 3)]);
        }
#pragma unroll
        for (int mt = 0; mt < 4; ++mt)
#pragma unroll
            for (int nt = 0; nt < 4; ++nt)
                acc[mt][nt] = __builtin_amdgcn_mfma_f32_16x16x32_bf16(af[mt], bf[nt], acc[mt][nt], 0, 0, 0);
    }

    __syncthreads();

    float bvals[4];
#pragma unroll
    for (int nt = 0; nt < 4; ++nt) bvals[nt] = bias[nbase + nq * 64 + nt * 16 + l15];

    if (z == 2) {
        // ---- V^T epilogue: block transpose, per-32 slot permutation.
        unsigned short* Epv = smem;            // [32 rows][136]
        const int hbase = nbase >> 6;
        const int b     = mbase >> 11;
        const int srow0 = mbase & 2047;
#pragma unroll
        for (int nt = 0; nt < 4; ++nt) {
            __syncthreads();
            short8 w[2];
#pragma unroll
            for (int e = 0; e < 2; ++e)
#pragma unroll
                for (int j = 0; j < 8; ++j) {
                    const int mt2 = 2 * e + (j >> 2), r = j & 3;
                    w[e][j] = (short)f2bf(acc[mt2][nt][r] + bvals[nt]);
                }
            unsigned short* dst = &Epv[(nq * 16 + l15) * 136 + mq * 64 + quad * 8];
            *(short8*)(dst)      = w[0];
            *(short8*)(dst + 32) = w[1];
            __syncthreads();
            const int row = tid >> 3;                    // 0..31
            const int d   = nt * 16 + (row & 15);
            const int h   = hbase + (row >> 4);
#pragma unroll
            for (int e = 0; e < 2; ++e) {
                const int colb = e * 64 + (tid & 7) * 8;
                short8 v = *(const short8*)(&Epv[row * 136 + colb]);
                *(short8*)(&out[((size_t)(b * 16 + h) * 64 + d) * 2048 + srow0 + colb]) = v;
            }
        }
    } else {
        // ---- Q/K epilogue: wave-local transpose -> 1 KB-contiguous stores
        unsigned short* Ep = smem + wave * 1152;         // [16 m][72]
        const int hQ = (nbase + nq * 64) >> 6;
        const float scl = (z == 0) ? 0.18033688f : 1.0f; // log2(e)/8 folded into Q
#pragma unroll
        for (int mt = 0; mt < 4; ++mt) {
#pragma unroll
            for (int nt = 0; nt < 4; ++nt)
#pragma unroll
                for (int r = 0; r < 4; ++r)
                    Ep[(quad * 4 + r) * 72 + nt * 16 + l15] =
                        f2bf((acc[mt][nt][r] + bvals[nt]) * scl);
#pragma unroll
            for (int half = 0; half < 2; ++half) {
                const int m = (lane >> 3) + half * 8;
                const int nblk = lane & 7;
                short8 v = *(const short8*)(&Ep[m * 72 + nblk * 8]);
                const int gm = mbase + mq * 64 + mt * 16 + m;
                const int b2 = gm >> 11, srw = gm & 2047;
                *(short8*)(&out[((size_t)(b2 * 16 + hQ) * 2048 + srw) * 64 + nblk * 8]) = v;
            }
        }
    }
}

// ---------------------------------------------------------------------------
// Kernel 2: flash attention, KV-split 8-wave blocks, register-only P.
//   Waves 0-3: KV tiles 0..15 (keys 0..1023);  waves 4-7: tiles 16..31.
//   Each half has its own 32 KB K/V double-buffer (64 KB total LDS).
//   Partials combine LINEARLY (no online max): O = O_A + O_B, l = l_A + l_B.
//   l accumulated via MFMA with all-ones A-fragment (matrix pipe, not VALU).
//   NEW: QK-MFMA / exp2 interleaved at mt granularity (feed matrix + trans
//   pipes from one wave's stream); ~0-2.9k cyc per-block phase stagger to
//   decorrelate the co-resident blocks' pipe bursts; setprio(1) around the
//   PV MFMA cluster.  grid (32 bh, 16 qt) x 512 thr.
// ---------------------------------------------------------------------------
__global__ __launch_bounds__(512, 4) void attn(
    const unsigned short* __restrict__ qb, const unsigned short* __restrict__ kb,
    const unsigned short* __restrict__ vtb, float* __restrict__ xw)
{
    const int tid  = threadIdx.x;
    const int wave = tid >> 6;            // 0..7
    const int wq   = wave & 3;            // q-subtile within block
    const int kvh  = wave >> 2;           // kv half (0: keys 0..1023, 1: 1024..2047)
    const int lane = tid & 63;
    const int l15  = lane & 15;
    const int quad = lane >> 4;

    const int bh    = blockIdx.x;
    const int qbase = blockIdx.y * 128 + wq * 32;

    __shared__ __align__(16) unsigned short smem[32768];   // 64 KB: 2 halves x (K|V dbuf); epilogue O
    __shared__ float Lsh[8][32];                           // per-wave l partials

    unsigned short* Ks0 = smem + kvh * 16384;   // this half's K dbuf: [2][4096]
    unsigned short* Vs0 = Ks0 + 8192;           // this half's V dbuf: [2][4096]

    // Q fragments, 2 q-tiles (pre-scaled by log2e/8)
    short8 qf[2][2];
#pragma unroll
    for (int nt = 0; nt < 2; ++nt) {
        const unsigned short* Qp = qb + ((size_t)bh * 2048 + qbase + nt * 16 + l15) * 64 + quad * 8;
        qf[nt][0] = *(const short8*)(Qp);
        qf[nt][1] = *(const short8*)(Qp + 32);
    }

    const unsigned short* Kbh = kb  + ((size_t)bh * 2048 + (size_t)kvh * 1024) * 64;  // [S][DK]
    const unsigned short* Vbh = vtb + (size_t)bh * 64 * 2048 + (size_t)kvh * 1024;    // [DK][Sperm]

    const int r8 = lane >> 3, c8 = lane & 7;
    const unsigned short *srcK[2], *srcV[2];
#pragma unroll
    for (int t = 0; t < 2; ++t) {
        const int row = wq * 16 + t * 8 + r8;
        srcK[t] = Kbh + (size_t)row * 64   + ((c8 ^ r8) << 3);
        srcV[t] = Vbh + (size_t)row * 2048 + ((c8 ^ r8) << 3);
    }

    // all-ones bf16 A-fragment for the l row-sum MFMA
    uint32x4 ou; ou[0] = ou[1] = ou[2] = ou[3] = 0x3F803F80u;
    const short8 onesf = __builtin_bit_cast(short8, ou);

    f32x4 lacc[2];
    f32x4 O[2][4];                      // O^T: [q-tile nt][d-tile dt]
#pragma unroll
    for (int nt = 0; nt < 2; ++nt) {
        lacc[nt] = (f32x4){0.f, 0.f, 0.f, 0.f};
#pragma unroll
        for (int i = 0; i < 4; ++i) O[nt][i] = (f32x4){0.f, 0.f, 0.f, 0.f};
    }

#pragma unroll
    for (int t = 0; t < 2; ++t) {
        g2l16(srcK[t], Ks0 + (wq * 16 + t * 8) * 64);
        g2l16(srcV[t], Vs0 + (wq * 16 + t * 8) * 64);
    }

    // ---- per-block phase stagger: 0..~2.9k cyc keyed on blockIdx, so the
    // co-resident blocks' MFMA/exp2/LDS bursts decorrelate (they are
    // independent barrier domains but otherwise evolve in lockstep).
    {
        const int stag = ((blockIdx.x * 5 + blockIdx.y * 3) & 7) * 6;
#pragma unroll 1
        for (int s = 0; s < stag; ++s)
            asm volatile("s_nop 7\n s_nop 7\n s_nop 7\n s_nop 7\n"
                         "s_nop 7\n s_nop 7\n s_nop 7\n s_nop 7" :::);
    }

    for (int it = 0; it < 16; ++it) {
        const int buf = it & 1;
        __syncthreads();                 // vmcnt(0) drain: tile `it` landed

        if (it + 1 < 16) {
            const size_t kn = (size_t)(it + 1) * 64;
#pragma unroll
            for (int t = 0; t < 2; ++t) {
                g2l16(srcK[t] + kn * 64, Ks0 + (buf ^ 1) * 4096 + (wq * 16 + t * 8) * 64);
                g2l16(srcV[t] + kn,      Vs0 + (buf ^ 1) * 4096 + (wq * 16 + t * 8) * 64);
            }
        }

        const unsigned short* Kb_ = Ks0 + buf * 4096;
        const unsigned short* Vb_ = Vs0 + buf * 4096;

        // ---- K A-fragments: K[s=mt*16+l15][d = dc*32+quad*8+j]
        short8 kf[4][2];
#pragma unroll
        for (int mt = 0; mt < 4; ++mt)
#pragma unroll
            for (int dc = 0; dc < 2; ++dc)
                kf[mt][dc] = *(const short8*)(&Kb_[(mt * 16 + l15) * 64 +
                                                  ((((dc << 2) + quad) ^ (l15 & 7)) << 3)]);

        // ---- S^T tiles interleaved with exp2: sc[mt][nt] holds
        // S^T[s=mt*16+quad*4+r][q=nt*16+l15]; exp(mt) issues between the
        // QK-MFMA groups of mt+1/mt+2 so matrix + trans pipes co-run.
        f32x4 sc[4][2];
#define QK_TILE(MT)                                                                  \
        do {                                                                          \
            _Pragma("unroll")                                                         \
            for (int nt = 0; nt < 2; ++nt) {                                          \
                f32x4 a = {0.f, 0.f, 0.f, 0.f};                                       \
                a = __builtin_amdgcn_mfma_f32_16x16x32_bf16(kf[MT][0], qf[nt][0], a, 0, 0, 0); \
                a = __builtin_amdgcn_mfma_f32_16x16x32_bf16(kf[MT][1], qf[nt][1], a, 0, 0, 0); \
                sc[MT][nt] = a;                                                       \
            }                                                                         \
        } while (0)
#define EXP_TILE(MT)                                                                 \
        do {                                                                          \
            _Pragma("unroll")                                                         \
            for (int nt = 0; nt < 2; ++nt)                                            \
                _Pragma("unroll")                                                     \
                for (int r = 0; r < 4; ++r)                                           \
                    sc[MT][nt][r] = __builtin_amdgcn_exp2f(sc[MT][nt][r]);            \
        } while (0)
        QK_TILE(0);
        QK_TILE(1);
        EXP_TILE(0);
        QK_TILE(2);
        EXP_TILE(1);
        QK_TILE(3);
        EXP_TILE(2);
        EXP_TILE(3);
#undef QK_TILE
#undef EXP_TILE

        // ---- PV: O^T += V^T(A) . P(B).  pf slots j<4 <- sc[2c], j>=4 <- sc[2c+1]
#pragma unroll
        for (int c = 0; c < 2; ++c) {
            short8 pf[2];
#pragma unroll
            for (int nt = 0; nt < 2; ++nt) {
                uint32x4 pu;
                pu[0] = packbf2(sc[2 * c][nt][0],     sc[2 * c][nt][1]);
                pu[1] = packbf2(sc[2 * c][nt][2],     sc[2 * c][nt][3]);
                pu[2] = packbf2(sc[2 * c + 1][nt][0], sc[2 * c + 1][nt][1]);
                pu[3] = packbf2(sc[2 * c + 1][nt][2], sc[2 * c + 1][nt][3]);
                pf[nt] = __builtin_bit_cast(short8, pu);
            }
            __builtin_amdgcn_s_setprio(1);
            // l row-sums on the matrix pipe: D[*][q] += sum_k P[k][q]
            lacc[0] = __builtin_amdgcn_mfma_f32_16x16x32_bf16(onesf, pf[0], lacc[0], 0, 0, 0);
            lacc[1] = __builtin_amdgcn_mfma_f32_16x16x32_bf16(onesf, pf[1], lacc[1], 0, 0, 0);
#pragma unroll
            for (int dt = 0; dt < 4; ++dt) {
                const short8 vf = *(const short8*)(&Vb_[(dt * 16 + l15) * 64 +
                                                       ((((c << 2) + quad) ^ (l15 & 7)) << 3)]);
                O[0][dt] = __builtin_amdgcn_mfma_f32_16x16x32_bf16(vf, pf[0], O[0][dt], 0, 0, 0);
                O[1][dt] = __builtin_amdgcn_mfma_f32_16x16x32_bf16(vf, pf[1], O[1][dt], 0, 0, 0);
            }
            __builtin_amdgcn_s_setprio(0);
        }
    }

    // ---- combine the two KV halves: O = O_A + O_B, l = l_A + l_B ----
    __syncthreads();                      // everyone done reading K/V LDS

    // l partials -> LDS (every lane with same l15 holds the same value)
    if (quad == 0) {
        Lsh[wave][l15]      = lacc[0][0];
        Lsh[wave][16 + l15] = lacc[1][0];
    }

    // unnormalized O^T -> LDS (wave-private 8 KB, XOR-swizzled cols)
    float* Ow = (float*)smem + wave * 2048;   // [32 q][64 d]
#pragma unroll
    for (int nt = 0; nt < 2; ++nt)
#pragma unroll
        for (int dt = 0; dt < 4; ++dt) {
            const int row  = nt * 16 + l15;
            const int c4s  = (dt * 4 + quad) ^ l15;        // swizzle: col4 ^ (row&15)
            *(f32x4*)(&Ow[row * 64 + c4s * 4]) = O[nt][dt];
        }
    __syncthreads();

    // wave pair (wq, wq+4) splits the 32 q rows: kvh=0 -> rows 0..15, kvh=1 -> 16..31
    const float* OwA = (float*)smem + wq * 2048;
    const float* OwB = (float*)smem + (wq + 4) * 2048;
    const int b = bh >> 4, h = bh & 15;
    const size_t obase = ((size_t)b * 2048 + qbase) * 1024 + h * 64 + lane;
#pragma unroll
    for (int j = 0; j < 16; ++j) {
        const int qq   = kvh * 16 + j;
        const float li = 1.0f / (Lsh[wq][qq] + Lsh[wq + 4][qq]);
        const int off  = qq * 64 + (((lane >> 2) ^ (qq & 15)) << 2) + (lane & 3);
        xw[obase + (size_t)qq * 1024] = (OwA[off] + OwB[off]) * li;
    }
}

// ---------------------------------------------------------------------------
// Kernel 3: residual + LayerNorm (eps = 1e-6).  One block per (b,s) row.
// ---------------------------------------------------------------------------
__global__ __launch_bounds__(256) void ln_kernel(
    const float* __restrict__ xw, const float* __restrict__ res,
    const float* __restrict__ gamma, const float* __restrict__ beta,
    float* __restrict__ out)
{
    const int row = blockIdx.x;
    const int tid = threadIdx.x;
    const size_t base = (size_t)row * 1024 + tid * 4;

    const float4 x  = *(const float4*)(xw + base);
    const float4 rv = *(const float4*)(res + base);
    float4 y;
    y.x = x.x + rv.x; y.y = x.y + rv.y; y.z = x.z + rv.z; y.w = x.w + rv.w;

    float s  = y.x + y.y + y.z + y.w;
    float s2 = y.x * y.x + y.y * y.y + y.z * y.z + y.w * y.w;
#pragma unroll
    for (int off = 32; off >= 1; off >>= 1) {
        s  += __shfl_xor(s, off);
        s2 += __shfl_xor(s2, off);
    }
    __shared__ float red[8];
    const int wave = tid >> 6;
    if ((tid & 63) == 0) { red[wave] = s; red[4 + wave] = s2; }
    __syncthreads();
    s  = red[0] + red[1] + red[2] + red[3];
    s2 = red[4] + red[5] + red[6] + red[7];

    const float mu   = s * (1.0f / 1024.0f);
    const float var  = s2 * (1.0f / 1024.0f) - mu * mu;
    const float rstd = rsqrtf(var + 1e-6f);

    const float4 g  = *(const float4*)(gamma + tid * 4);
    const float4 bt = *(const float4*)(beta + tid * 4);
    float4 o;
    o.x = (y.x - mu) * rstd * g.x + bt.x;
    o.y = (y.y - mu) * rstd * g.y + bt.y;
    o.z = (y.z - mu) * rstd * g.z + bt.z;
    o.w = (y.w - mu) * rstd * g.w + bt.w;
    *(float4*)(out + base) = o;
}

// ---------------------------------------------------------------------------
extern "C" void kernel_launch(void* const* d_in, const int* in_sizes, int n_in,
                              void* d_out, int out_size, void* d_ws, size_t ws_size,
                              hipStream_t stream) {
    const float* query = (const float*)d_in[0];
    const float* key_  = (const float*)d_in[1];
    const float* value = (const float*)d_in[2];
    const float* Wq    = (const float*)d_in[3];
    const float* bq    = (const float*)d_in[4];
    const float* Wk    = (const float*)d_in[5];
    const float* bk    = (const float*)d_in[6];
    const float* Wv    = (const float*)d_in[7];
    const float* bv    = (const float*)d_in[8];
    const float* ln_g  = (const float*)d_in[9];
    const float* ln_b  = (const float*)d_in[10];
    float* out = (float*)d_out;

    // ws layout (54 MB): [0,24M) Xb (dead after qkv; aliased by xw 16 MB),
    // [24,30M) Wtb, [30,38M) qb, [38,46M) kb, [46,54M) vtb
    const size_t MB = 1024 * 1024;
    char* ws = (char*)d_ws;
    unsigned short* Xbuf = (unsigned short*)(ws);
    float*          xwp  = (float*)(ws);
    unsigned short* Wtb  = (unsigned short*)(ws + 24 * MB);
    unsigned short* qbuf = (unsigned short*)(ws + 30 * MB);
    unsigned short* kbuf = (unsigned short*)(ws + 38 * MB);
    unsigned short* vtb  = (unsigned short*)(ws + 46 * MB);

    convert_all<<<6912,           256, 0, stream>>>(query, key_, value, Wq, Wk, Wv, Xbuf, Wtb);
    qkv_gemm   <<<dim3(32, 8, 3), 256, 0, stream>>>(Xbuf, Wtb, bq, bk, bv, qbuf, kbuf, vtb);
    attn       <<<dim3(32, 16),   512, 0, stream>>>(qbuf, kbuf, vtb, xwp);
    ln_kernel  <<<4096,           256, 0, stream>>>(xwp, query, ln_g, ln_b, out);
}

// Round 5
// 196.261 us; speedup vs baseline: 1.4093x; 1.0448x over previous
//
#include <hip/hip_runtime.h>

// B=2, S=2048, D=1024, H=16, DK=64.  BH = 32, M = B*S = 4096.
// convert_w (W -> W^T bf16 only) -> qkv_gemm (A-path: fused f32->bf16
// conversion via reg-staging, T14 issue-early/write-late; B-path g2l16;
// Q pre-scaled log2e/8) -> attn (round-2 best: flash, KV-split 8-wave
// blocks, register-only P, l via ones-MFMA) -> ln.

typedef float f32x4 __attribute__((ext_vector_type(4)));
typedef short short8 __attribute__((ext_vector_type(8)));
typedef unsigned int uint32x4 __attribute__((ext_vector_type(4)));

__device__ __forceinline__ unsigned short f2bf(float f) {
    unsigned u = __builtin_bit_cast(unsigned, f);
    u += 0x7fffu + ((u >> 16) & 1u);          // round-to-nearest-even
    return (unsigned short)(u >> 16);
}
// pack two floats -> two bf16 (truncation) in ONE v_perm_b32
__device__ __forceinline__ unsigned packbf2(float lo, float hi) {
    return __builtin_amdgcn_perm(__builtin_bit_cast(unsigned, hi),
                                 __builtin_bit_cast(unsigned, lo), 0x07060302u);
}

// async global->LDS, 16 B per lane; dest = wave-uniform base + lane*16
__device__ __forceinline__ void g2l16(const unsigned short* g, unsigned short* l) {
    __builtin_amdgcn_global_load_lds(
        (const __attribute__((address_space(1))) unsigned int*)g,
        (__attribute__((address_space(3))) unsigned int*)l, 16, 0, 0);
}

// convert 8 f32 (two float4) -> short8 bf16, store 16 B to LDS
__device__ __forceinline__ void cvt_store8(unsigned short* d, float4 a, float4 b) {
    short8 o;
    o[0] = (short)f2bf(a.x); o[1] = (short)f2bf(a.y);
    o[2] = (short)f2bf(a.z); o[3] = (short)f2bf(a.w);
    o[4] = (short)f2bf(b.x); o[5] = (short)f2bf(b.y);
    o[6] = (short)f2bf(b.z); o[7] = (short)f2bf(b.w);
    *(short8*)d = o;
}

// ---------------------------------------------------------------------------
// Kernel 0: W -> W^T bf16 (LDS-tiled transpose).  768 blocks only.
// ---------------------------------------------------------------------------
__global__ __launch_bounds__(256) void convert_w(
    const float* __restrict__ Wq, const float* __restrict__ Wk, const float* __restrict__ Wv,
    unsigned short* __restrict__ wout)
{
    const int i = blockIdx.x;
    const int tid = threadIdx.x;
    const int z = i >> 8, tile = i & 255;
    const float* W = (z == 0) ? Wq : (z == 1) ? Wk : Wv;
    unsigned short* Wt = wout + (size_t)z * 1048576;
    __shared__ unsigned short Ts[64 * 65];
    const int kb0 = (tile >> 4) * 64, nb0 = (tile & 15) * 64;
    const int a = tid >> 6, b = tid & 63;
#pragma unroll
    for (int j = 0; j < 16; ++j) {
        const int k = j * 4 + a, n = b;
        Ts[n * 65 + k] = f2bf(W[(size_t)(kb0 + k) * 1024 + nb0 + n]);
    }
    __syncthreads();
#pragma unroll
    for (int j = 0; j < 16; ++j) {
        const int n = j * 4 + a, k = b;
        Wt[(size_t)(nb0 + n) * 1024 + kb0 + k] = Ts[n * 65 + k];
    }
}

// ---------------------------------------------------------------------------
// Kernel 1: QKV GEMM (bf16 MFMA, 128x128 tile, BK=32, dbuf).
// A-path: reads X in f32 DIRECTLY from the op inputs, converts to bf16 in
// registers, ds_write_b128 into the same swizzled LDS layout g2l16 produced
// (chunk c of row r holds k-chunk c^(r&3)).  Loads issued right after the
// barrier; convert+write after the MFMA block (latency hidden, T14).
// B-path: g2l16 (async) of pre-transposed bf16 W^T.
// Q,K -> [B,H,S,DK]; V -> [B,H,DK,Sperm] with per-32 slot-perm matching the
// attn S^T register layout.
// ---------------------------------------------------------------------------
__global__ __launch_bounds__(256) void qkv_gemm(
    const float* __restrict__ xq, const float* __restrict__ xk, const float* __restrict__ xv,
    const unsigned short* __restrict__ Wtb,
    const float* __restrict__ bq, const float* __restrict__ bk, const float* __restrict__ bv,
    unsigned short* __restrict__ qo, unsigned short* __restrict__ ko, unsigned short* __restrict__ vo)
{
    const int z = blockIdx.z;
    const float* Xf = (z == 0) ? xq : (z == 1) ? xk : xv;
    const unsigned short* Wt = Wtb + (size_t)z * 1048576;
    const float* bias   = (z == 0) ? bq : (z == 1) ? bk : bv;
    unsigned short* out = (z == 0) ? qo : (z == 1) ? ko : vo;

    __shared__ unsigned short smem[16384];    // 32 KB: dbuf A|B; epilogue reuses

    const int tid  = threadIdx.x;
    const int wave = tid >> 6;
    const int lane = tid & 63;
    const int l15  = lane & 15;
    const int quad = lane >> 4;
    const int mq   = wave & 1, nq = wave >> 1;
    const int mbase = blockIdx.x * 128, nbase = blockIdx.y * 128;

    const int srow = lane >> 2;               // 0..15
    const int schk = (lane & 3) ^ (srow & 3); // permuted k-chunk for this lane

    // A (f32 source): t=0 rows wave*32+srow, t=1 rows +16
    const float* srcA0 = Xf + (size_t)(mbase + wave * 32 + srow) * 1024 + schk * 8;
    const float* srcA1 = srcA0 + 16 * 1024;
    // A LDS dest (shorts): row*32 + (lane&3)*8  — identical to g2l16's layout
    unsigned short* dstA0 = &smem[(wave * 32 + srow) * 32 + (lane & 3) * 8];
    unsigned short* dstA1 = dstA0 + 16 * 32;

    const unsigned short* srcB = Wt + (size_t)(nbase + wave * 32 + srow) * 1024 + schk * 8;

    f32x4 acc[4][4];
#pragma unroll
    for (int i = 0; i < 4; ++i)
#pragma unroll
        for (int j = 0; j < 4; ++j) acc[i][j] = (f32x4){0.f, 0.f, 0.f, 0.f};

    // ---- prologue: stage tile 0 (A synchronous reg-convert, B async)
#pragma unroll
    for (int t = 0; t < 2; ++t)
        g2l16(srcB + (size_t)t * 16 * 1024, &smem[4096 + (wave * 32 + t * 16) * 32]);
    {
        const float4 x0 = *(const float4*)(srcA0);
        const float4 x1 = *(const float4*)(srcA0 + 4);
        const float4 y0 = *(const float4*)(srcA1);
        const float4 y1 = *(const float4*)(srcA1 + 4);
        cvt_store8(dstA0, x0, x1);
        cvt_store8(dstA1, y0, y1);
    }

    for (int it = 0; it < 32; ++it) {
        const int boff = (it & 1) * 8192;
        const int poff = boff ^ 8192;
        __syncthreads();

        float4 a0, a1, c0, c1;
        if (it + 1 < 32) {
            const size_t ko2 = (size_t)(it + 1) * 32;
#pragma unroll
            for (int t = 0; t < 2; ++t)
                g2l16(srcB + (size_t)t * 16 * 1024 + ko2, &smem[poff + 4096 + (wave * 32 + t * 16) * 32]);
            a0 = *(const float4*)(srcA0 + ko2);
            a1 = *(const float4*)(srcA0 + ko2 + 4);
            c0 = *(const float4*)(srcA1 + ko2);
            c1 = *(const float4*)(srcA1 + ko2 + 4);
        }

        short8 af[4], bf[4];
#pragma unroll
        for (int i = 0; i < 4; ++i) {
            af[i] = *(const short8*)(&smem[boff + (mq * 64 + i * 16 + l15) * 32 + ((quad ^ (l15 & 3)) << 3)]);
            bf[i] = *(const short8*)(&smem[boff + 4096 + (nq * 64 + i * 16 + l15) * 32 + ((quad ^ (l15 & 3)) << 3)]);
        }
#pragma unroll
        for (int mt = 0; mt < 4; ++mt)
#pragma unroll
            for (int nt = 0; nt < 4; ++nt)
                acc[mt][nt] = __builtin_amdgcn_mfma_f32_16x16x32_bf16(af[mt], bf[nt], acc[mt][nt], 0, 0, 0);

        if (it + 1 < 32) {
            cvt_store8(dstA0 + poff, a0, a1);
            cvt_store8(dstA1 + poff, c0, c1);
        }
    }

    __syncthreads();

    float bvals[4];
#pragma unroll
    for (int nt = 0; nt < 4; ++nt) bvals[nt] = bias[nbase + nq * 64 + nt * 16 + l15];

    if (z == 2) {
        // ---- V^T epilogue: block transpose, per-32 slot permutation.
        unsigned short* Epv = smem;            // [32 rows][136]
        const int hbase = nbase >> 6;
        const int b     = mbase >> 11;
        const int srow0 = mbase & 2047;
#pragma unroll
        for (int nt = 0; nt < 4; ++nt) {
            __syncthreads();
            short8 w[2];
#pragma unroll
            for (int e = 0; e < 2; ++e)
#pragma unroll
                for (int j = 0; j < 8; ++j) {
                    const int mt2 = 2 * e + (j >> 2), r = j & 3;
                    w[e][j] = (short)f2bf(acc[mt2][nt][r] + bvals[nt]);
                }
            unsigned short* dst = &Epv[(nq * 16 + l15) * 136 + mq * 64 + quad * 8];
            *(short8*)(dst)      = w[0];
            *(short8*)(dst + 32) = w[1];
            __syncthreads();
            const int row = tid >> 3;                    // 0..31
            const int d   = nt * 16 + (row & 15);
            const int h   = hbase + (row >> 4);
#pragma unroll
            for (int e = 0; e < 2; ++e) {
                const int colb = e * 64 + (tid & 7) * 8;
                short8 v = *(const short8*)(&Epv[row * 136 + colb]);
                *(short8*)(&out[((size_t)(b * 16 + h) * 64 + d) * 2048 + srow0 + colb]) = v;
            }
        }
    } else {
        // ---- Q/K epilogue: wave-local transpose -> 1 KB-contiguous stores
        unsigned short* Ep = smem + wave * 1152;         // [16 m][72]
        const int hQ = (nbase + nq * 64) >> 6;
        const float scl = (z == 0) ? 0.18033688f : 1.0f; // log2(e)/8 folded into Q
#pragma unroll
        for (int mt = 0; mt < 4; ++mt) {
#pragma unroll
            for (int nt = 0; nt < 4; ++nt)
#pragma unroll
                for (int r = 0; r < 4; ++r)
                    Ep[(quad * 4 + r) * 72 + nt * 16 + l15] =
                        f2bf((acc[mt][nt][r] + bvals[nt]) * scl);
#pragma unroll
            for (int half = 0; half < 2; ++half) {
                const int m = (lane >> 3) + half * 8;
                const int nblk = lane & 7;
                short8 v = *(const short8*)(&Ep[m * 72 + nblk * 8]);
                const int gm = mbase + mq * 64 + mt * 16 + m;
                const int b2 = gm >> 11, srw = gm & 2047;
                *(short8*)(&out[((size_t)(b2 * 16 + hQ) * 2048 + srw) * 64 + nblk * 8]) = v;
            }
        }
    }
}

// ---------------------------------------------------------------------------
// Kernel 2: flash attention, KV-split 8-wave blocks, register-only P.
//   (round-2 structure — best measured: 46.1 µs)
//   Waves 0-3: KV tiles 0..15 (keys 0..1023);  waves 4-7: tiles 16..31.
//   Each half has its own 32 KB K/V double-buffer (64 KB total LDS).
//   No online max => partials combine LINEARLY: O = O_A + O_B, l = l_A + l_B.
//   l accumulated via MFMA with all-ones A-fragment (matrix pipe, not VALU).
//   Epilogue O^T staged into the (dead) K/V LDS with XOR swizzle.
// ---------------------------------------------------------------------------
__global__ __launch_bounds__(512, 4) void attn(
    const unsigned short* __restrict__ qb, const unsigned short* __restrict__ kb,
    const unsigned short* __restrict__ vtb, float* __restrict__ xw)
{
    const int tid  = threadIdx.x;
    const int wave = tid >> 6;            // 0..7
    const int wq   = wave & 3;            // q-subtile within block
    const int kvh  = wave >> 2;           // kv half (0: keys 0..1023, 1: 1024..2047)
    const int lane = tid & 63;
    const int l15  = lane & 15;
    const int quad = lane >> 4;

    const int bh    = blockIdx.x;
    const int qbase = blockIdx.y * 128 + wq * 32;

    __shared__ __align__(16) unsigned short smem[32768];   // 64 KB: 2 halves x (K|V dbuf); epilogue O
    __shared__ float Lsh[8][32];                           // per-wave l partials

    unsigned short* Ks0 = smem + kvh * 16384;   // this half's K dbuf: [2][4096]
    unsigned short* Vs0 = Ks0 + 8192;           // this half's V dbuf: [2][4096]

    // Q fragments, 2 q-tiles (pre-scaled by log2e/8)
    short8 qf[2][2];
#pragma unroll
    for (int nt = 0; nt < 2; ++nt) {
        const unsigned short* Qp = qb + ((size_t)bh * 2048 + qbase + nt * 16 + l15) * 64 + quad * 8;
        qf[nt][0] = *(const short8*)(Qp);
        qf[nt][1] = *(const short8*)(Qp + 32);
    }

    const unsigned short* Kbh = kb  + ((size_t)bh * 2048 + (size_t)kvh * 1024) * 64;  // [S][DK]
    const unsigned short* Vbh = vtb + (size_t)bh * 64 * 2048 + (size_t)kvh * 1024;    // [DK][Sperm]

    const int r8 = lane >> 3, c8 = lane & 7;
    const unsigned short *srcK[2], *srcV[2];
#pragma unroll
    for (int t = 0; t < 2; ++t) {
        const int row = wq * 16 + t * 8 + r8;
        srcK[t] = Kbh + (size_t)row * 64   + ((c8 ^ r8) << 3);
        srcV[t] = Vbh + (size_t)row * 2048 + ((c8 ^ r8) << 3);
    }

    // all-ones bf16 A-fragment for the l row-sum MFMA
    uint32x4 ou; ou[0] = ou[1] = ou[2] = ou[3] = 0x3F803F80u;
    const short8 onesf = __builtin_bit_cast(short8, ou);

    f32x4 lacc[2];
    f32x4 O[2][4];                      // O^T: [q-tile nt][d-tile dt]
#pragma unroll
    for (int nt = 0; nt < 2; ++nt) {
        lacc[nt] = (f32x4){0.f, 0.f, 0.f, 0.f};
#pragma unroll
        for (int i = 0; i < 4; ++i) O[nt][i] = (f32x4){0.f, 0.f, 0.f, 0.f};
    }

#pragma unroll
    for (int t = 0; t < 2; ++t) {
        g2l16(srcK[t], Ks0 + (wq * 16 + t * 8) * 64);
        g2l16(srcV[t], Vs0 + (wq * 16 + t * 8) * 64);
    }

    for (int it = 0; it < 16; ++it) {
        const int buf = it & 1;
        __syncthreads();                 // vmcnt(0) drain: tile `it` landed

        if (it + 1 < 16) {
            const size_t kn = (size_t)(it + 1) * 64;
#pragma unroll
            for (int t = 0; t < 2; ++t) {
                g2l16(srcK[t] + kn * 64, Ks0 + (buf ^ 1) * 4096 + (wq * 16 + t * 8) * 64);
                g2l16(srcV[t] + kn,      Vs0 + (buf ^ 1) * 4096 + (wq * 16 + t * 8) * 64);
            }
        }

        const unsigned short* Kb_ = Ks0 + buf * 4096;
        const unsigned short* Vb_ = Vs0 + buf * 4096;

        // ---- K A-fragments: K[s=mt*16+l15][d = dc*32+quad*8+j]
        short8 kf[4][2];
#pragma unroll
        for (int mt = 0; mt < 4; ++mt)
#pragma unroll
            for (int dc = 0; dc < 2; ++dc)
                kf[mt][dc] = *(const short8*)(&Kb_[(mt * 16 + l15) * 64 +
                                                  ((((dc << 2) + quad) ^ (l15 & 7)) << 3)]);

        // ---- S^T tiles: sc[mt][nt] holds S^T[s=mt*16+quad*4+r][q=nt*16+l15]
        f32x4 sc[4][2];
#pragma unroll
        for (int mt = 0; mt < 4; ++mt)
#pragma unroll
            for (int nt = 0; nt < 2; ++nt) {
                f32x4 a = {0.f, 0.f, 0.f, 0.f};
                a = __builtin_amdgcn_mfma_f32_16x16x32_bf16(kf[mt][0], qf[nt][0], a, 0, 0, 0);
                a = __builtin_amdgcn_mfma_f32_16x16x32_bf16(kf[mt][1], qf[nt][1], a, 0, 0, 0);
                sc[mt][nt] = a;
            }

        // ---- p = exp2(s) in regs (l comes from the ones-MFMA below)
#pragma unroll
        for (int mt = 0; mt < 4; ++mt)
#pragma unroll
            for (int nt = 0; nt < 2; ++nt)
#pragma unroll
                for (int r = 0; r < 4; ++r)
                    sc[mt][nt][r] = __builtin_amdgcn_exp2f(sc[mt][nt][r]);

        // ---- PV: O^T += V^T(A) . P(B).  pf slots j<4 <- sc[2c], j>=4 <- sc[2c+1]
#pragma unroll
        for (int c = 0; c < 2; ++c) {
            short8 pf[2];
#pragma unroll
            for (int nt = 0; nt < 2; ++nt) {
                uint32x4 pu;
                pu[0] = packbf2(sc[2 * c][nt][0],     sc[2 * c][nt][1]);
                pu[1] = packbf2(sc[2 * c][nt][2],     sc[2 * c][nt][3]);
                pu[2] = packbf2(sc[2 * c + 1][nt][0], sc[2 * c + 1][nt][1]);
                pu[3] = packbf2(sc[2 * c + 1][nt][2], sc[2 * c + 1][nt][3]);
                pf[nt] = __builtin_bit_cast(short8, pu);
            }
            // l row-sums on the matrix pipe: D[*][q] += sum_k P[k][q]
            lacc[0] = __builtin_amdgcn_mfma_f32_16x16x32_bf16(onesf, pf[0], lacc[0], 0, 0, 0);
            lacc[1] = __builtin_amdgcn_mfma_f32_16x16x32_bf16(onesf, pf[1], lacc[1], 0, 0, 0);
#pragma unroll
            for (int dt = 0; dt < 4; ++dt) {
                const short8 vf = *(const short8*)(&Vb_[(dt * 16 + l15) * 64 +
                                                       ((((c << 2) + quad) ^ (l15 & 7)) << 3)]);
                O[0][dt] = __builtin_amdgcn_mfma_f32_16x16x32_bf16(vf, pf[0], O[0][dt], 0, 0, 0);
                O[1][dt] = __builtin_amdgcn_mfma_f32_16x16x32_bf16(vf, pf[1], O[1][dt], 0, 0, 0);
            }
        }
    }

    // ---- combine the two KV halves: O = O_A + O_B, l = l_A + l_B ----
    __syncthreads();                      // everyone done reading K/V LDS

    // l partials -> LDS (every lane with same l15 holds the same value)
    if (quad == 0) {
        Lsh[wave][l15]      = lacc[0][0];
        Lsh[wave][16 + l15] = lacc[1][0];
    }

    // unnormalized O^T -> LDS (wave-private 8 KB, XOR-swizzled cols)
    float* Ow = (float*)smem + wave * 2048;   // [32 q][64 d]
#pragma unroll
    for (int nt = 0; nt < 2; ++nt)
#pragma unroll
        for (int dt = 0; dt < 4; ++dt) {
            const int row  = nt * 16 + l15;
            const int c4s  = (dt * 4 + quad) ^ l15;        // swizzle: col4 ^ (row&15)
            *(f32x4*)(&Ow[row * 64 + c4s * 4]) = O[nt][dt];
        }
    __syncthreads();

    // wave pair (wq, wq+4) splits the 32 q rows: kvh=0 -> rows 0..15, kvh=1 -> 16..31
    const float* OwA = (float*)smem + wq * 2048;
    const float* OwB = (float*)smem + (wq + 4) * 2048;
    const int b = bh >> 4, h = bh & 15;
    const size_t obase = ((size_t)b * 2048 + qbase) * 1024 + h * 64 + lane;
#pragma unroll
    for (int j = 0; j < 16; ++j) {
        const int qq   = kvh * 16 + j;
        const float li = 1.0f / (Lsh[wq][qq] + Lsh[wq + 4][qq]);
        const int off  = qq * 64 + (((lane >> 2) ^ (qq & 15)) << 2) + (lane & 3);
        xw[obase + (size_t)qq * 1024] = (OwA[off] + OwB[off]) * li;
    }
}

// ---------------------------------------------------------------------------
// Kernel 3: residual + LayerNorm (eps = 1e-6).  One block per (b,s) row.
// ---------------------------------------------------------------------------
__global__ __launch_bounds__(256) void ln_kernel(
    const float* __restrict__ xw, const float* __restrict__ res,
    const float* __restrict__ gamma, const float* __restrict__ beta,
    float* __restrict__ out)
{
    const int row = blockIdx.x;
    const int tid = threadIdx.x;
    const size_t base = (size_t)row * 1024 + tid * 4;

    const float4 x  = *(const float4*)(xw + base);
    const float4 rv = *(const float4*)(res + base);
    float4 y;
    y.x = x.x + rv.x; y.y = x.y + rv.y; y.z = x.z + rv.z; y.w = x.w + rv.w;

    float s  = y.x + y.y + y.z + y.w;
    float s2 = y.x * y.x + y.y * y.y + y.z * y.z + y.w * y.w;
#pragma unroll
    for (int off = 32; off >= 1; off >>= 1) {
        s  += __shfl_xor(s, off);
        s2 += __shfl_xor(s2, off);
    }
    __shared__ float red[8];
    const int wave = tid >> 6;
    if ((tid & 63) == 0) { red[wave] = s; red[4 + wave] = s2; }
    __syncthreads();
    s  = red[0] + red[1] + red[2] + red[3];
    s2 = red[4] + red[5] + red[6] + red[7];

    const float mu   = s * (1.0f / 1024.0f);
    const float var  = s2 * (1.0f / 1024.0f) - mu * mu;
    const float rstd = rsqrtf(var + 1e-6f);

    const float4 g  = *(const float4*)(gamma + tid * 4);
    const float4 bt = *(const float4*)(beta + tid * 4);
    float4 o;
    o.x = (y.x - mu) * rstd * g.x + bt.x;
    o.y = (y.y - mu) * rstd * g.y + bt.y;
    o.z = (y.z - mu) * rstd * g.z + bt.z;
    o.w = (y.w - mu) * rstd * g.w + bt.w;
    *(float4*)(out + base) = o;
}

// ---------------------------------------------------------------------------
extern "C" void kernel_launch(void* const* d_in, const int* in_sizes, int n_in,
                              void* d_out, int out_size, void* d_ws, size_t ws_size,
                              hipStream_t stream) {
    const float* query = (const float*)d_in[0];
    const float* key_  = (const float*)d_in[1];
    const float* value = (const float*)d_in[2];
    const float* Wq    = (const float*)d_in[3];
    const float* bq    = (const float*)d_in[4];
    const float* Wk    = (const float*)d_in[5];
    const float* bk    = (const float*)d_in[6];
    const float* Wv    = (const float*)d_in[7];
    const float* bv    = (const float*)d_in[8];
    const float* ln_g  = (const float*)d_in[9];
    const float* ln_b  = (const float*)d_in[10];
    float* out = (float*)d_out;

    // ws layout (54 MB): [0,16M) xw, [24,30M) Wtb,
    // [30,38M) qb, [38,46M) kb, [46,54M) vtb
    const size_t MB = 1024 * 1024;
    char* ws = (char*)d_ws;
    float*          xwp  = (float*)(ws);
    unsigned short* Wtb  = (unsigned short*)(ws + 24 * MB);
    unsigned short* qbuf = (unsigned short*)(ws + 30 * MB);
    unsigned short* kbuf = (unsigned short*)(ws + 38 * MB);
    unsigned short* vtb  = (unsigned short*)(ws + 46 * MB);

    convert_w  <<<768,            256, 0, stream>>>(Wq, Wk, Wv, Wtb);
    qkv_gemm   <<<dim3(32, 8, 3), 256, 0, stream>>>(query, key_, value, Wtb, bq, bk, bv, qbuf, kbuf, vtb);
    attn       <<<dim3(32, 16),   512, 0, stream>>>(qbuf, kbuf, vtb, xwp);
    ln_kernel  <<<4096,           256, 0, stream>>>(xwp, query, ln_g, ln_b, out);
}